// Round 12
// baseline (993.169 us; speedup 1.0000x reference)
//
#include <hip/hip_runtime.h>
#include <hip/hip_bf16.h>

namespace {
constexpr int Bn = 512;
constexpr int Ln = 1024;
constexpr int Vn = 64;
constexpr int En = 128;
constexpr int Kc = Vn + En;              // 192
constexpr size_t SEQB_BYTES  = (size_t)Bn * Ln * Vn * 2;  // 67,108,864
constexpr size_t WALLB_BYTES = (size_t)En * Kc * 2;       // 49,152
constexpr size_t BC_BYTES    = En * 4;                    // 512
constexpr size_t WOUTP_BYTES = (size_t)Vn * En * 2;       // 16,384
constexpr size_t FAST_WS  = SEQB_BYTES + WALLB_BYTES + BC_BYTES;               // LDS path
constexpr size_t FAST_WS2 = SEQB_BYTES + WALLB_BYTES + BC_BYTES + WOUTP_BYTES; // reg path
}

typedef __attribute__((ext_vector_type(8))) short bf16x8;
typedef __attribute__((ext_vector_type(4))) float f32x4;
typedef __attribute__((ext_vector_type(8))) unsigned short u16x8;

__device__ __forceinline__ unsigned f2b(float f) {
  unsigned u = __float_as_uint(f);
  u += 0x7fffu + ((u >> 16) & 1u);
  return u >> 16;
}
__device__ __forceinline__ float b2f(unsigned short b) {
  return __uint_as_float(((unsigned)b) << 16);
}
__device__ __forceinline__ bf16x8 pack8(const float* v) {
  bf16x8 r;
#pragma unroll
  for (int i = 0; i < 8; ++i) r[i] = (short)f2b(v[i]);
  return r;
}

// column permutation for the LDS h cycle:
// z k-tile tau, frag elem e=4*hi+i at k-group lg  <->  h col 32*tau + 16*hi + 4*lg + i
// -> m(kk) = 32*(kk>>5) + 16*((kk>>2)&1) + 4*((kk>>3)&3) + (kk&3)
__device__ __forceinline__ int cm4(int kk) {
  return 32 * (kk >> 5) + 16 * ((kk >> 2) & 1) + 4 * ((kk >> 3) & 3) + (kk & 3);
}

#define MFMA __builtin_amdgcn_mfma_f32_16x16x32_bf16

// ---------------- setup kernels ----------------

__global__ void seq_cvt(const float* __restrict__ seq, unsigned short* __restrict__ seqb) {
  const size_t n = (size_t)Bn * Ln * Vn;
  size_t i = ((size_t)blockIdx.x * blockDim.x + threadIdx.x) * 8;
  const size_t stride = (size_t)gridDim.x * blockDim.x * 8;
  for (; i < n; i += stride) {
    const f32x4 a = *(const f32x4*)(seq + i);
    const f32x4 b = *(const f32x4*)(seq + i + 4);
    u16x8 o;
#pragma unroll
    for (int j = 0; j < 4; ++j) o[j] = (unsigned short)f2b(a[j]);
#pragma unroll
    for (int j = 0; j < 4; ++j) o[4 + j] = (unsigned short)f2b(b[j]);
    *(u16x8*)(seqb + i) = o;
  }
}

// Wall2[j][k] bf16: k<64 -> folded input proj; k>=64 -> Whh[j][cm4(k-64)]
__global__ void rnn_setup2(const float* __restrict__ W_in, const float* __restrict__ b_in,
                           const float* __restrict__ W_h, const float* __restrict__ b_h,
                           unsigned short* __restrict__ wall2, float* __restrict__ bc) {
  const int j = blockIdx.x;    // 0..127
  const int k = threadIdx.x;   // 0..191
  const float* whr = W_h + j * (2 * En);
  float s;
  if (k < Vn) {
    s = 0.f;
#pragma unroll 8
    for (int e = 0; e < En; ++e) s = fmaf(W_in[e * Vn + k], whr[e], s);
  } else {
    s = whr[En + cm4(k - Vn)];
  }
  wall2[j * Kc + k] = (unsigned short)f2b(s);
  if (k == 0) {
    float b = b_h[j];
    for (int e = 0; e < En; ++e) b = fmaf(b_in[e], whr[e], b);
    bc[j] = b;
  }
}

__global__ void wout_setup(const float* __restrict__ W_out, unsigned short* __restrict__ woutp) {
  const int v = blockIdx.x;    // 0..63
  const int kk = threadIdx.x;  // 0..127
  woutp[v * En + kk] = (unsigned short)f2b(W_out[(size_t)v * En + cm4(kk)]);
}

// ---------------- main kernel: dual-chain interleave, 8 waves ----------------
// Block handles TWO independent batch groups (A: rows r0..r0+15, B: +16..+31).
// Every wave runs both chains phase-shifted in one instruction stream per
// barrier interval: A+B z-reads issue together; A's dependent MFMA chain runs
// under B's read latency and vice versa; the h-independent seq-MFMAs for step
// t+1 are computed in step t's drain shadow. One lgkm-drain + barrier per
// superstep advances both chains -> serial chain amortized over 2 steps.
// Exchange layout per chain (proven in r10): tile tau = 1024B, consumer lane l
// at byte l*16 (conflict-free b128); producer uint2 at l*16 + 8*hi.
__global__ __launch_bounds__(512, 1) void rnn_dual(
    const unsigned short* __restrict__ seqb, const unsigned short* __restrict__ wall2,
    const float* __restrict__ bc, const unsigned short* __restrict__ woutp,
    const float* __restrict__ b_out, float* __restrict__ out) {
  __shared__ __align__(16) unsigned char zlds[2][2][4096];  // [chain][buf][4 tiles x 1024B]

  const int tid = threadIdx.x;
  const int w   = tid >> 6;        // wave 0..7, owns n-tile w (h cols 16w..16w+15)
  const int tau = w >> 1;          // k-tile this wave's output feeds
  const int hi  = w & 1;           // half within the tile frag
  const int l   = tid & 63;
  const int l15 = l & 15;          // batch col / A row
  const int lg  = l >> 4;          // k-group / C row-group
  const int r0  = blockIdx.x * 32;

  // weights (shared by both chains): Aw[0,1] = seq k-tiles; Aw[2+p] = z k-tile p
  bf16x8 Aw[6];
  {
    const unsigned short* row = wall2 + (size_t)(16 * w + l15) * Kc + lg * 8;
    Aw[0] = *(const bf16x8*)(row);
    Aw[1] = *(const bf16x8*)(row + 32);
#pragma unroll
    for (int p = 0; p < 4; ++p) Aw[2 + p] = *(const bf16x8*)(row + Vn + 32 * p);
  }
  const f32x4 bcv = *(const f32x4*)(bc + 16 * w + 4 * lg);

  const int ro = l * 16;                      // read slot (per tile)
  const int wo = tau * 1024 + ro + hi * 8;    // write slot (within buffer)

  // h(0) = 0 for both chains
  for (int i = tid; i < 4096; i += 512) ((unsigned int*)zlds)[i] = 0u;

  const unsigned short* sqbA = seqb + ((size_t)(r0 + l15) * Ln) * Vn + lg * 8;
  const unsigned short* sqbB = seqb + ((size_t)(r0 + 16 + l15) * Ln) * Vn + lg * 8;
  bf16x8 sregA[4][2], sregB[4][2];

#define SEQ_PFA(BI, T)                                                \
  { const int tp = ((T) < Ln) ? (T) : (Ln - 1);                       \
    const bf16x8* sp = (const bf16x8*)(sqbA + (size_t)tp * Vn);       \
    sregA[BI][0] = sp[0];                                             \
    sregA[BI][1] = sp[4]; }
#define SEQ_PFB(BI, T)                                                \
  { const int tp = ((T) < Ln) ? (T) : (Ln - 1);                       \
    const bf16x8* sp = (const bf16x8*)(sqbB + (size_t)tp * Vn);       \
    sregB[BI][0] = sp[0];                                             \
    sregB[BI][1] = sp[4]; }

  SEQ_PFA(0, 0) SEQ_PFB(0, 0)
  SEQ_PFA(1, 1) SEQ_PFB(1, 1)
  SEQ_PFA(2, 2) SEQ_PFB(2, 2)
  __syncthreads();

  // seq contribution of step 0, both chains (h-independent)
  f32x4 spA = MFMA(Aw[0], sregA[0][0], bcv, 0, 0, 0);
  spA = MFMA(Aw[1], sregA[0][1], spA, 0, 0, 0);
  f32x4 spB = MFMA(Aw[0], sregB[0][0], bcv, 0, 0, 0);
  spB = MFMA(Aw[1], sregB[0][1], spB, 0, 0, 0);

#define PHASE(P)                                                              \
  {                                                                           \
    const int cb = (P) & 1, nb = cb ^ 1;                                      \
    const unsigned char* baseA = zlds[0][cb];                                 \
    const unsigned char* baseB = zlds[1][cb];                                 \
    const bf16x8 zA0 = *(const bf16x8*)(baseA + ro);                          \
    const bf16x8 zA1 = *(const bf16x8*)(baseA + 1024 + ro);                   \
    const bf16x8 zA2 = *(const bf16x8*)(baseA + 2048 + ro);                   \
    const bf16x8 zA3 = *(const bf16x8*)(baseA + 3072 + ro);                   \
    const bf16x8 zB0 = *(const bf16x8*)(baseB + ro);                          \
    const bf16x8 zB1 = *(const bf16x8*)(baseB + 1024 + ro);                   \
    const bf16x8 zB2 = *(const bf16x8*)(baseB + 2048 + ro);                   \
    const bf16x8 zB3 = *(const bf16x8*)(baseB + 3072 + ro);                   \
    SEQ_PFA(((P) + 3) & 3, t + (P) + 3);                                      \
    SEQ_PFB(((P) + 3) & 3, t + (P) + 3);                                      \
    /* chain A: depth-2 dependent chain on top of precomputed seq part */     \
    f32x4 pA = MFMA(Aw[2], zA0, spA, 0, 0, 0);                                \
    f32x4 qA = {0.f, 0.f, 0.f, 0.f};                                          \
    qA = MFMA(Aw[3], zA1, qA, 0, 0, 0);                                       \
    pA = MFMA(Aw[4], zA2, pA, 0, 0, 0);                                       \
    qA = MFMA(Aw[5], zA3, qA, 0, 0, 0);                                       \
    /* A's next-step seq part (independent) fills the pipe */                 \
    spA = MFMA(Aw[0], sregA[((P) + 1) & 3][0], bcv, 0, 0, 0);                 \
    spA = MFMA(Aw[1], sregA[((P) + 1) & 3][1], spA, 0, 0, 0);                 \
    const f32x4 aA = pA + qA;                                                 \
    const float a0A = fmaxf(aA[0], 0.f), a1A = fmaxf(aA[1], 0.f);             \
    const float a2A = fmaxf(aA[2], 0.f), a3A = fmaxf(aA[3], 0.f);             \
    uint2 zoA;                                                                \
    asm("v_cvt_pk_bf16_f32 %0, %1, %2" : "=v"(zoA.x) : "v"(a0A), "v"(a1A));   \
    asm("v_cvt_pk_bf16_f32 %0, %1, %2" : "=v"(zoA.y) : "v"(a2A), "v"(a3A));   \
    *(uint2*)(zlds[0][nb] + wo) = zoA;                                        \
    /* chain B: reads long since landed; its chain overlaps A's tail */       \
    f32x4 pB = MFMA(Aw[2], zB0, spB, 0, 0, 0);                                \
    f32x4 qB = {0.f, 0.f, 0.f, 0.f};                                          \
    qB = MFMA(Aw[3], zB1, qB, 0, 0, 0);                                       \
    pB = MFMA(Aw[4], zB2, pB, 0, 0, 0);                                       \
    qB = MFMA(Aw[5], zB3, qB, 0, 0, 0);                                       \
    spB = MFMA(Aw[0], sregB[((P) + 1) & 3][0], bcv, 0, 0, 0);                 \
    spB = MFMA(Aw[1], sregB[((P) + 1) & 3][1], spB, 0, 0, 0);                 \
    const f32x4 aB = pB + qB;                                                 \
    const float a0B = fmaxf(aB[0], 0.f), a1B = fmaxf(aB[1], 0.f);             \
    const float a2B = fmaxf(aB[2], 0.f), a3B = fmaxf(aB[3], 0.f);             \
    uint2 zoB;                                                                \
    asm("v_cvt_pk_bf16_f32 %0, %1, %2" : "=v"(zoB.x) : "v"(a0B), "v"(a1B));   \
    asm("v_cvt_pk_bf16_f32 %0, %1, %2" : "=v"(zoB.y) : "v"(a2B), "v"(a3B));   \
    *(uint2*)(zlds[1][nb] + wo) = zoB;                                        \
    asm volatile("s_waitcnt lgkmcnt(0)" ::: "memory");                        \
    __builtin_amdgcn_s_barrier();                                             \
    asm volatile("" ::: "memory");                                            \
  }

#pragma unroll 1
  for (int t = 0; t < Ln; t += 4) {
    PHASE(0)
    PHASE(1)
    PHASE(2)
    PHASE(3)
  }
#undef PHASE
#undef SEQ_PFA
#undef SEQ_PFB

  // epilogue: h(1024) of both chains in buf0. Waves 0-3 -> chain A vocab
  // tiles 0-3; waves 4-7 -> chain B vocab tiles 0-3.
  {
    const int gc = w >> 2;       // chain
    const int wv = w & 3;        // vocab tile
    const unsigned char* zb = zlds[gc][0];
    f32x4 o = *(const f32x4*)(b_out + 16 * wv + 4 * lg);
    const unsigned short* wrow = woutp + (size_t)(16 * wv + l15) * En + lg * 8;
#pragma unroll
    for (int p2 = 0; p2 < 4; ++p2) {
      const bf16x8 zt = *(const bf16x8*)(zb + p2 * 1024 + ro);
      const bf16x8 wf = *(const bf16x8*)(wrow + 32 * p2);
      o = MFMA(wf, zt, o, 0, 0, 0);
    }
    *(f32x4*)&out[(size_t)(r0 + gc * 16 + l15) * Vn + 16 * wv + 4 * lg] = o;
  }
}

// ---------------- round-6 LDS fast path (fallback #1) ----------------

__global__ void rnn_setup_bf(const float* __restrict__ W_in, const float* __restrict__ b_in,
                             const float* __restrict__ W_h, const float* __restrict__ b_h,
                             unsigned short* __restrict__ wallb, float* __restrict__ bc) {
  const int j = blockIdx.x;
  const int k = threadIdx.x;
  const float* whr = W_h + j * (2 * En);
  float s;
  if (k < Vn) {
    s = 0.f;
#pragma unroll 8
    for (int e = 0; e < En; ++e) s = fmaf(W_in[e * Vn + k], whr[e], s);
  } else {
    s = whr[Vn + k];
  }
  wallb[j * Kc + k] = (unsigned short)f2b(s);
  if (k == 0) {
    float b = b_h[j];
    for (int e = 0; e < En; ++e) b = fmaf(b_in[e], whr[e], b);
    bc[j] = b;
  }
}

__global__ __launch_bounds__(128, 1) void rnn_fast2(
    const unsigned short* __restrict__ seqb, const unsigned short* __restrict__ wallb,
    const float* __restrict__ bc, const float* __restrict__ W_out,
    const float* __restrict__ b_out, float* __restrict__ out) {
  __shared__ __align__(16) unsigned char hbB[2][4096];

  const int tid = threadIdx.x;
  const int w   = tid >> 6;
  const int l   = tid & 63;
  const int l15 = l & 15;
  const int lg  = l >> 4;
  const int r0  = blockIdx.x * 16;
  const int swz = (l15 & 7) << 4;

  bf16x8 Aw[4][6];
  f32x4 bcv[4];
#pragma unroll
  for (int nn = 0; nn < 4; ++nn) {
    const int n = 4 * w + nn;
    const unsigned short* p = wallb + (size_t)(16 * n + l15) * Kc + lg * 8;
#pragma unroll
    for (int kt = 0; kt < 6; ++kt) Aw[nn][kt] = *(const bf16x8*)(p + kt * 32);
    bcv[nn] = *(const f32x4*)(bc + 16 * n + 4 * lg);
  }

  for (int i = tid; i < 2048; i += 128) ((unsigned int*)hbB)[i] = 0u;

  const unsigned short* sqb = seqb + ((size_t)(r0 + l15) * Ln) * Vn + lg * 8;
  bf16x8 sreg[4][2];

#define SEQ_PF(BI, T)                                                \
  { const int tp = ((T) < Ln) ? (T) : (Ln - 1);                      \
    const bf16x8* sp = (const bf16x8*)(sqb + (size_t)tp * Vn);       \
    sreg[BI][0] = sp[0];                                             \
    sreg[BI][1] = sp[4]; }

  SEQ_PF(0, 0)
  SEQ_PF(1, 1)
  SEQ_PF(2, 2)
  __syncthreads();

#define PHASE(P)                                                               \
  {                                                                            \
    const int cb = (P) & 1;                                                    \
    const unsigned char* zb = hbB[cb] + l15 * 256;                             \
    const bf16x8 z0 = *(const bf16x8*)(zb + ((16 * lg) ^ swz));                \
    const bf16x8 z1 = *(const bf16x8*)(zb + ((64 + 16 * lg) ^ swz));           \
    const bf16x8 z2 = *(const bf16x8*)(zb + ((128 + 16 * lg) ^ swz));          \
    const bf16x8 z3 = *(const bf16x8*)(zb + ((192 + 16 * lg) ^ swz));          \
    SEQ_PF(((P) + 3) & 3, t + (P) + 3);                                        \
    const bf16x8 s0 = sreg[(P)][0], s1 = sreg[(P)][1];                         \
    f32x4 p0 = bcv[0], p1 = bcv[1], p2 = bcv[2], p3 = bcv[3];                  \
    f32x4 q0 = {0.f, 0.f, 0.f, 0.f}, q1 = {0.f, 0.f, 0.f, 0.f};                \
    f32x4 q2 = {0.f, 0.f, 0.f, 0.f}, q3 = {0.f, 0.f, 0.f, 0.f};                \
    p0 = MFMA(Aw[0][0], s0, p0, 0, 0, 0);                                      \
    p1 = MFMA(Aw[1][0], s0, p1, 0, 0, 0);                                      \
    p2 = MFMA(Aw[2][0], s0, p2, 0, 0, 0);                                      \
    p3 = MFMA(Aw[3][0], s0, p3, 0, 0, 0);                                      \
    q0 = MFMA(Aw[0][1], s1, q0, 0, 0, 0);                                      \
    q1 = MFMA(Aw[1][1], s1, q1, 0, 0, 0);                                      \
    q2 = MFMA(Aw[2][1], s1, q2, 0, 0, 0);                                      \
    q3 = MFMA(Aw[3][1], s1, q3, 0, 0, 0);                                      \
    p0 = MFMA(Aw[0][2], z0, p0, 0, 0, 0);                                      \
    p1 = MFMA(Aw[1][2], z0, p1, 0, 0, 0);                                      \
    p2 = MFMA(Aw[2][2], z0, p2, 0, 0, 0);                                      \
    p3 = MFMA(Aw[3][2], z0, p3, 0, 0, 0);                                      \
    q0 = MFMA(Aw[0][3], z1, q0, 0, 0, 0);                                      \
    q1 = MFMA(Aw[1][3], z1, q1, 0, 0, 0);                                      \
    q2 = MFMA(Aw[2][3], z1, q2, 0, 0, 0);                                      \
    q3 = MFMA(Aw[3][3], z1, q3, 0, 0, 0);                                      \
    p0 = MFMA(Aw[0][4], z2, p0, 0, 0, 0);                                      \
    p1 = MFMA(Aw[1][4], z2, p1, 0, 0, 0);                                      \
    p2 = MFMA(Aw[2][4], z2, p2, 0, 0, 0);                                      \
    p3 = MFMA(Aw[3][4], z2, p3, 0, 0, 0);                                      \
    q0 = MFMA(Aw[0][5], z3, q0, 0, 0, 0);                                      \
    q1 = MFMA(Aw[1][5], z3, q1, 0, 0, 0);                                      \
    q2 = MFMA(Aw[2][5], z3, q2, 0, 0, 0);                                      \
    q3 = MFMA(Aw[3][5], z3, q3, 0, 0, 0);                                      \
    unsigned char* wbB = hbB[cb ^ 1] + l15 * 256;                              \
    _Pragma("unroll") for (int nn = 0; nn < 4; ++nn) {                         \
      const f32x4 pp = (nn == 0) ? p0 : (nn == 1) ? p1 : (nn == 2) ? p2 : p3;  \
      const f32x4 qq = (nn == 0) ? q0 : (nn == 1) ? q1 : (nn == 2) ? q2 : q3;  \
      const float r0v = fmaxf(pp[0] + qq[0], 0.f);                             \
      const float r1v = fmaxf(pp[1] + qq[1], 0.f);                             \
      const float r2v = fmaxf(pp[2] + qq[2], 0.f);                             \
      const float r3v = fmaxf(pp[3] + qq[3], 0.f);                             \
      unsigned d0, d1;                                                         \
      asm("v_cvt_pk_bf16_f32 %0, %1, %2" : "=v"(d0) : "v"(r0v), "v"(r1v));     \
      asm("v_cvt_pk_bf16_f32 %0, %1, %2" : "=v"(d1) : "v"(r2v), "v"(r3v));     \
      uint2 dd; dd.x = d0; dd.y = d1;                                          \
      *(uint2*)(wbB + ((128 * w + 32 * nn + 8 * lg) ^ swz)) = dd;              \
    }                                                                          \
    asm volatile("s_waitcnt lgkmcnt(0)" ::: "memory");                         \
    __builtin_amdgcn_s_barrier();                                              \
    asm volatile("" ::: "memory");                                             \
  }

#pragma unroll 1
  for (int t = 0; t < Ln; t += 4) {
    PHASE(0)
    PHASE(1)
    PHASE(2)
    PHASE(3)
  }
#undef PHASE
#undef SEQ_PF

  bf16x8 hz[4];
  const unsigned char* zb0 = hbB[0] + l15 * 256;
#pragma unroll
  for (int kt = 0; kt < 4; ++kt)
    hz[kt] = *(const bf16x8*)(zb0 + ((64 * kt + 16 * lg) ^ swz));
#pragma unroll
  for (int m = 0; m < 2; ++m) {
    const int v = 16 * (2 * w + m) + l15;
    const float* wor = W_out + (size_t)v * En + lg * 8;
    const float bo = b_out[v];
    f32x4 oa = {bo, bo, bo, bo};
#pragma unroll
    for (int kt = 0; kt < 4; ++kt) {
      float tmp[8];
      const float* p = wor + kt * 32;
#pragma unroll
      for (int i = 0; i < 8; ++i) tmp[i] = p[i];
      oa = MFMA(hz[kt], pack8(tmp), oa, 0, 0, 0);
    }
#pragma unroll
    for (int i = 0; i < 4; ++i)
      out[(size_t)(r0 + 4 * lg + i) * Vn + v] = oa[i];
  }
}

// ---------------- fp32 fallback (no workspace needed) ----------------

__global__ __launch_bounds__(256, 1) void rnn_mfma(
    const float* __restrict__ seq, const float* __restrict__ W_in,
    const float* __restrict__ b_in, const float* __restrict__ W_h,
    const float* __restrict__ b_h, const float* __restrict__ W_out,
    const float* __restrict__ b_out, float* __restrict__ out) {
  __shared__ __align__(16) unsigned short hb[2][16][136];

  const int tid = threadIdx.x;
  const int w   = tid >> 6;
  const int l   = tid & 63;
  const int l15 = l & 15;
  const int lg  = l >> 4;
  const int r0  = blockIdx.x * 16;

  bf16x8 Bw[2][6];
  float bc[2];
#pragma unroll
  for (int n = 0; n < 2; ++n) {
    const int j = 32 * w + 16 * n + l15;
    const float* whr = W_h + j * (2 * En);
    float b = b_h[j];
    for (int e = 0; e < En; ++e) b = fmaf(b_in[e], whr[e], b);
    bc[n] = b;
#pragma unroll
    for (int kt = 0; kt < 6; ++kt) {
      float v[8];
#pragma unroll
      for (int i = 0; i < 8; ++i) {
        const int k = kt * 32 + lg * 8 + i;
        if (k < Vn) {
          float s = 0.f;
          for (int e = 0; e < En; ++e) s = fmaf(W_in[e * Vn + k], whr[e], s);
          v[i] = s;
        } else {
          v[i] = whr[Vn + k];
        }
      }
      Bw[n][kt] = pack8(v);
    }
  }

  for (int i = tid; i < 2 * 16 * 136; i += 256) ((unsigned short*)hb)[i] = 0;

  const float* sq = seq + ((size_t)(r0 + l15) * Ln) * Vn + lg * 8;
  f32x4 sbuf[4][4];

#define SEQ_PF(BI, T)                                                 \
  { const int tp = ((T) < Ln) ? (T) : (Ln - 1);                       \
    const f32x4* p0 = (const f32x4*)(sq + (size_t)tp * Vn);           \
    const f32x4* p1 = (const f32x4*)(sq + (size_t)tp * Vn + 32);      \
    sbuf[BI][0] = p0[0]; sbuf[BI][1] = p0[1];                         \
    sbuf[BI][2] = p1[0]; sbuf[BI][3] = p1[1]; }

  SEQ_PF(0, 0)
  SEQ_PF(1, 1)
  SEQ_PF(2, 2)
  __syncthreads();

#define PHASE(P)                                                              \
  {                                                                           \
    const int cb = (P) & 1, nb = cb ^ 1;                                      \
    const bf16x8 h0 = *(const bf16x8*)&hb[cb][l15][lg * 8];                   \
    const bf16x8 h1 = *(const bf16x8*)&hb[cb][l15][32 + lg * 8];              \
    const bf16x8 h2 = *(const bf16x8*)&hb[cb][l15][64 + lg * 8];              \
    const bf16x8 h3 = *(const bf16x8*)&hb[cb][l15][96 + lg * 8];              \
    SEQ_PF(((P) + 3) & 3, t + (P) + 3);                                       \
    float v0[8], v1[8];                                                       \
    _Pragma("unroll") for (int i = 0; i < 4; ++i) {                           \
      v0[i] = sbuf[(P)][0][i]; v0[4 + i] = sbuf[(P)][1][i];                   \
      v1[i] = sbuf[(P)][2][i]; v1[4 + i] = sbuf[(P)][3][i];                   \
    }                                                                         \
    const bf16x8 a0 = pack8(v0), a1 = pack8(v1);                              \
    f32x4 p0a = {bc[0], bc[0], bc[0], bc[0]};                                 \
    f32x4 p1a = {bc[1], bc[1], bc[1], bc[1]};                                 \
    f32x4 q0a = {0.f, 0.f, 0.f, 0.f}, q1a = {0.f, 0.f, 0.f, 0.f};             \
    p0a = MFMA(a0, Bw[0][0], p0a, 0, 0, 0);                                   \
    p1a = MFMA(a0, Bw[1][0], p1a, 0, 0, 0);                                   \
    p0a = MFMA(a1, Bw[0][1], p0a, 0, 0, 0);                                   \
    p1a = MFMA(a1, Bw[1][1], p1a, 0, 0, 0);                                   \
    p0a = MFMA(h0, Bw[0][2], p0a, 0, 0, 0);                                   \
    p1a = MFMA(h0, Bw[1][2], p1a, 0, 0, 0);                                   \
    q0a = MFMA(h2, Bw[0][4], q0a, 0, 0, 0);                                   \
    q1a = MFMA(h2, Bw[1][4], q1a, 0, 0, 0);                                   \
    p0a = MFMA(h1, Bw[0][3], p0a, 0, 0, 0);                                   \
    p1a = MFMA(h1, Bw[1][3], p1a, 0, 0, 0);                                   \
    q0a = MFMA(h3, Bw[0][5], q0a, 0, 0, 0);                                   \
    q1a = MFMA(h3, Bw[1][5], q1a, 0, 0, 0);                                   \
    const int j0 = 32 * w + l15, j1 = j0 + 16, rr = 4 * lg;                   \
    _Pragma("unroll") for (int i = 0; i < 4; ++i) {                           \
      hb[nb][rr + i][j0] = (unsigned short)f2b(fmaxf(p0a[i] + q0a[i], 0.f));  \
      hb[nb][rr + i][j1] = (unsigned short)f2b(fmaxf(p1a[i] + q1a[i], 0.f));  \
    }                                                                         \
    asm volatile("s_waitcnt lgkmcnt(0)" ::: "memory");                        \
    __builtin_amdgcn_s_barrier();                                             \
    asm volatile("" ::: "memory");                                            \
  }

#pragma unroll 1
  for (int t = 0; t < Ln; t += 4) {
    PHASE(0)
    PHASE(1)
    PHASE(2)
    PHASE(3)
  }
#undef PHASE
#undef SEQ_PF

  const int orow = tid >> 4;
  const int oc   = (tid & 15) * 4;
  float o0 = b_out[oc], o1 = b_out[oc + 1], o2 = b_out[oc + 2], o3 = b_out[oc + 3];
  const float* w0 = W_out + (size_t)(oc + 0) * En;
  const float* w1 = W_out + (size_t)(oc + 1) * En;
  const float* w2 = W_out + (size_t)(oc + 2) * En;
  const float* w3 = W_out + (size_t)(oc + 3) * En;
#pragma unroll 8
  for (int k = 0; k < En; ++k) {
    const float hv = b2f(hb[0][orow][k]);
    o0 = fmaf(hv, w0[k], o0);
    o1 = fmaf(hv, w1[k], o1);
    o2 = fmaf(hv, w2[k], o2);
    o3 = fmaf(hv, w3[k], o3);
  }
  *(float4*)&out[(size_t)(r0 + orow) * Vn + oc] = make_float4(o0, o1, o2, o3);
}

extern "C" void kernel_launch(void* const* d_in, const int* in_sizes, int n_in,
                              void* d_out, int out_size, void* d_ws, size_t ws_size,
                              hipStream_t stream) {
  const float* seq   = (const float*)d_in[0];
  const float* W_in  = (const float*)d_in[1];
  const float* b_in  = (const float*)d_in[2];
  const float* W_h   = (const float*)d_in[3];
  const float* b_h   = (const float*)d_in[4];
  const float* W_out = (const float*)d_in[5];
  const float* b_out = (const float*)d_in[6];
  float* out = (float*)d_out;

  if (ws_size >= FAST_WS2) {
    unsigned short* seqb  = (unsigned short*)d_ws;
    unsigned short* wall2 = (unsigned short*)((char*)d_ws + SEQB_BYTES);
    float* bc             = (float*)((char*)d_ws + SEQB_BYTES + WALLB_BYTES);
    unsigned short* woutp = (unsigned short*)((char*)d_ws + SEQB_BYTES + WALLB_BYTES + BC_BYTES);
    seq_cvt<<<2048, 256, 0, stream>>>(seq, seqb);
    rnn_setup2<<<En, Kc, 0, stream>>>(W_in, b_in, W_h, b_h, wall2, bc);
    wout_setup<<<Vn, En, 0, stream>>>(W_out, woutp);
    rnn_dual<<<Bn / 32, 512, 0, stream>>>(seqb, wall2, bc, woutp, b_out, out);
  } else if (ws_size >= FAST_WS) {
    unsigned short* seqb  = (unsigned short*)d_ws;
    unsigned short* wallb = (unsigned short*)((char*)d_ws + SEQB_BYTES);
    float* bc = (float*)((char*)d_ws + SEQB_BYTES + WALLB_BYTES);
    seq_cvt<<<2048, 256, 0, stream>>>(seq, seqb);
    rnn_setup_bf<<<En, Kc, 0, stream>>>(W_in, b_in, W_h, b_h, wallb, bc);
    rnn_fast2<<<Bn / 16, 128, 0, stream>>>(seqb, wallb, bc, W_out, b_out, out);
  } else {
    rnn_mfma<<<Bn / 16, 256, 0, stream>>>(seq, W_in, b_in, W_h, b_h, W_out, b_out, out);
  }
}

// Round 13
// 281.202 us; speedup vs baseline: 3.5319x; 3.5319x over previous
//
#include <hip/hip_runtime.h>
#include <hip/hip_bf16.h>

namespace {
constexpr int Bn = 512;
constexpr int Ln = 1024;
constexpr int Vn = 64;
constexpr int En = 128;
constexpr int Kc = Vn + En;              // 192
constexpr size_t SEQB_BYTES  = (size_t)Bn * Ln * Vn * 2;  // 67,108,864
constexpr size_t WALLB_BYTES = (size_t)En * Kc * 2;       // 49,152
constexpr size_t BC_BYTES    = En * 4;                    // 512
constexpr size_t WOUTP_BYTES = (size_t)Vn * En * 2;       // 16,384
constexpr size_t FAST_WS  = SEQB_BYTES + WALLB_BYTES + BC_BYTES;               // LDS path
constexpr size_t FAST_WS2 = SEQB_BYTES + WALLB_BYTES + BC_BYTES + WOUTP_BYTES; // reg path
}

typedef __attribute__((ext_vector_type(8))) short bf16x8;
typedef __attribute__((ext_vector_type(4))) float f32x4;
typedef __attribute__((ext_vector_type(8))) unsigned short u16x8;

__device__ __forceinline__ unsigned f2b(float f) {
  unsigned u = __float_as_uint(f);
  u += 0x7fffu + ((u >> 16) & 1u);
  return u >> 16;
}
__device__ __forceinline__ float b2f(unsigned short b) {
  return __uint_as_float(((unsigned)b) << 16);
}
__device__ __forceinline__ bf16x8 pack8(const float* v) {
  bf16x8 r;
#pragma unroll
  for (int i = 0; i < 8; ++i) r[i] = (short)f2b(v[i]);
  return r;
}

// column permutation for the h cycle:
// k-tile tau, frag elem e at k-group lg:  kk = 32*tau + 8*lg + e
// -> h col m(kk) = 32*tau + 16*(e>>2) + 4*lg + (e&3)
// m(kk) = 32*(kk>>5) + 16*((kk>>2)&1) + 4*((kk>>3)&3) + (kk&3)
__device__ __forceinline__ int cm4(int kk) {
  return 32 * (kk >> 5) + 16 * ((kk >> 2) & 1) + 4 * ((kk >> 3) & 3) + (kk & 3);
}

#define MFMA __builtin_amdgcn_mfma_f32_16x16x32_bf16

// ---------------- setup kernels ----------------

__global__ void seq_cvt(const float* __restrict__ seq, unsigned short* __restrict__ seqb) {
  const size_t n = (size_t)Bn * Ln * Vn;
  size_t i = ((size_t)blockIdx.x * blockDim.x + threadIdx.x) * 8;
  const size_t stride = (size_t)gridDim.x * blockDim.x * 8;
  for (; i < n; i += stride) {
    const f32x4 a = *(const f32x4*)(seq + i);
    const f32x4 b = *(const f32x4*)(seq + i + 4);
    u16x8 o;
#pragma unroll
    for (int j = 0; j < 4; ++j) o[j] = (unsigned short)f2b(a[j]);
#pragma unroll
    for (int j = 0; j < 4; ++j) o[4 + j] = (unsigned short)f2b(b[j]);
    *(u16x8*)(seqb + i) = o;
  }
}

// Wall2[j][k] bf16: k<64 -> folded input proj; k>=64 -> Whh[j][cm4(k-64)]
__global__ void rnn_setup2(const float* __restrict__ W_in, const float* __restrict__ b_in,
                           const float* __restrict__ W_h, const float* __restrict__ b_h,
                           unsigned short* __restrict__ wall2, float* __restrict__ bc) {
  const int j = blockIdx.x;    // 0..127
  const int k = threadIdx.x;   // 0..191
  const float* whr = W_h + j * (2 * En);
  float s;
  if (k < Vn) {
    s = 0.f;
#pragma unroll 8
    for (int e = 0; e < En; ++e) s = fmaf(W_in[e * Vn + k], whr[e], s);
  } else {
    s = whr[En + cm4(k - Vn)];
  }
  wall2[j * Kc + k] = (unsigned short)f2b(s);
  if (k == 0) {
    float b = b_h[j];
    for (int e = 0; e < En; ++e) b = fmaf(b_in[e], whr[e], b);
    bc[j] = b;
  }
}

__global__ void wout_setup(const float* __restrict__ W_out, unsigned short* __restrict__ woutp) {
  const int v = blockIdx.x;    // 0..63
  const int kk = threadIdx.x;  // 0..127
  woutp[v * En + kk] = (unsigned short)f2b(W_out[(size_t)v * En + cm4(kk)]);
}

// ---------------- main kernel: 4 waves (1/SIMD), 12 MFMA/wave, own tile in reg ----
// Wave w owns n-tiles {2w,2w+1} = h cols [32w,32w+32) = k-tile w. Under cm4 its
// packed relu output IS its own complete 16B B-frag (zown, register-resident).
// Per step: 3 foreign ds_read_b128 (conflict-free lane-linear layout), 1
// ds_write_b128 of zown, 12 MFMAs; the 6 foreign-independent MFMAs (4 seq +
// 2 zown) issue under the read latency. 1 wave/SIMD avoids the 8-wave
// contention wall (r10/r12 evidence); MFMA issue ~36cyc/wave dominates.
__global__ __launch_bounds__(256, 1) void rnn_quad(
    const unsigned short* __restrict__ seqb, const unsigned short* __restrict__ wall2,
    const float* __restrict__ bc, const unsigned short* __restrict__ woutp,
    const float* __restrict__ b_out, float* __restrict__ out) {
  __shared__ __align__(16) unsigned char zlds[2][4][1024];  // [buf][tile][lane16B]

  const int tid = threadIdx.x;
  const int w   = tid >> 6;        // wave 0..3 = owned k-tile
  const int l   = tid & 63;
  const int l15 = l & 15;          // batch col / A row
  const int lg  = l >> 4;          // k-group / C row-group
  const int r0  = blockIdx.x * 16;

  // weights for n-tiles 2w (Aw[0]) and 2w+1 (Aw[1]); [kt]: 0,1=seq, 2+p=z tile (w+p)&3
  bf16x8 Aw[2][6];
#pragma unroll
  for (int nn = 0; nn < 2; ++nn) {
    const unsigned short* row = wall2 + (size_t)(16 * (2 * w + nn) + l15) * Kc + lg * 8;
    Aw[nn][0] = *(const bf16x8*)(row);
    Aw[nn][1] = *(const bf16x8*)(row + 32);
#pragma unroll
    for (int p = 0; p < 4; ++p)
      Aw[nn][2 + p] = *(const bf16x8*)(row + Vn + 32 * ((w + p) & 3));
  }
  const f32x4 bcv0 = *(const f32x4*)(bc + 32 * w + 4 * lg);
  const f32x4 bcv1 = *(const f32x4*)(bc + 32 * w + 16 + 4 * lg);

  const int ro  = l * 16;  // lane slot within a tile (stride-1, conflict-free)
  const unsigned char* rA1 = &zlds[0][(w + 1) & 3][ro];
  const unsigned char* rA2 = &zlds[0][(w + 2) & 3][ro];
  const unsigned char* rA3 = &zlds[0][(w + 3) & 3][ro];
  const unsigned char* rB1 = &zlds[1][(w + 1) & 3][ro];
  const unsigned char* rB2 = &zlds[1][(w + 2) & 3][ro];
  const unsigned char* rB3 = &zlds[1][(w + 3) & 3][ro];
  unsigned char* wA = &zlds[0][w][ro];
  unsigned char* wB = &zlds[1][w][ro];

  // h(0) = 0
  for (int i = tid; i < 2048; i += 256) ((unsigned int*)zlds)[i] = 0u;
  bf16x8 zown;
#pragma unroll
  for (int i = 0; i < 8; ++i) zown[i] = 0;

  const unsigned short* sqb = seqb + ((size_t)(r0 + l15) * Ln) * Vn + lg * 8;
  bf16x8 sreg[4][2];

#define SEQ_PF(BI, T)                                                \
  { const int tp = ((T) < Ln) ? (T) : (Ln - 1);                      \
    const bf16x8* sp = (const bf16x8*)(sqb + (size_t)tp * Vn);       \
    sreg[BI][0] = sp[0];                                             \
    sreg[BI][1] = sp[4]; }

  SEQ_PF(0, 0)
  SEQ_PF(1, 1)
  SEQ_PF(2, 2)
  __syncthreads();

  // step: read 3 foreign tiles of z(t) from buf[t&1]; own tile = zown (reg).
  // compute h(t+1); pack -> zown; write zown to buf[(t+1)&1]; drain; barrier.
#define PHASE(P, R1, R2, R3, WR)                                              \
  {                                                                           \
    const bf16x8 zf1 = *(const bf16x8*)(R1);                                  \
    const bf16x8 zf2 = *(const bf16x8*)(R2);                                  \
    const bf16x8 zf3 = *(const bf16x8*)(R3);                                  \
    SEQ_PF(((P) + 3) & 3, t + (P) + 3);                                       \
    const bf16x8 s0 = sreg[(P)][0], s1 = sreg[(P)][1];                        \
    /* foreign-independent first: 4 seq + 2 zown MFMAs hide read latency */   \
    f32x4 p0 = MFMA(Aw[0][0], s0, bcv0, 0, 0, 0);                             \
    f32x4 p1 = MFMA(Aw[1][0], s0, bcv1, 0, 0, 0);                             \
    f32x4 q0 = {0.f, 0.f, 0.f, 0.f}, q1 = {0.f, 0.f, 0.f, 0.f};               \
    q0 = MFMA(Aw[0][1], s1, q0, 0, 0, 0);                                     \
    q1 = MFMA(Aw[1][1], s1, q1, 0, 0, 0);                                     \
    p0 = MFMA(Aw[0][2], zown, p0, 0, 0, 0);                                   \
    p1 = MFMA(Aw[1][2], zown, p1, 0, 0, 0);                                   \
    q0 = MFMA(Aw[0][3], zf1, q0, 0, 0, 0);                                    \
    q1 = MFMA(Aw[1][3], zf1, q1, 0, 0, 0);                                    \
    p0 = MFMA(Aw[0][4], zf2, p0, 0, 0, 0);                                    \
    p1 = MFMA(Aw[1][4], zf2, p1, 0, 0, 0);                                    \
    q0 = MFMA(Aw[0][5], zf3, q0, 0, 0, 0);                                    \
    q1 = MFMA(Aw[1][5], zf3, q1, 0, 0, 0);                                    \
    const f32x4 a0 = p0 + q0, a1 = p1 + q1;                                   \
    const float x0 = fmaxf(a0[0], 0.f), x1 = fmaxf(a0[1], 0.f);               \
    const float x2 = fmaxf(a0[2], 0.f), x3 = fmaxf(a0[3], 0.f);               \
    const float y0 = fmaxf(a1[0], 0.f), y1 = fmaxf(a1[1], 0.f);               \
    const float y2 = fmaxf(a1[2], 0.f), y3 = fmaxf(a1[3], 0.f);               \
    unsigned u0, u1, u2, u3;                                                  \
    asm("v_cvt_pk_bf16_f32 %0, %1, %2" : "=v"(u0) : "v"(x0), "v"(x1));        \
    asm("v_cvt_pk_bf16_f32 %0, %1, %2" : "=v"(u1) : "v"(x2), "v"(x3));        \
    asm("v_cvt_pk_bf16_f32 %0, %1, %2" : "=v"(u2) : "v"(y0), "v"(y1));        \
    asm("v_cvt_pk_bf16_f32 %0, %1, %2" : "=v"(u3) : "v"(y2), "v"(y3));        \
    union { unsigned u[4]; bf16x8 v; } zc;                                    \
    zc.u[0] = u0; zc.u[1] = u1; zc.u[2] = u2; zc.u[3] = u3;                   \
    zown = zc.v;                                                              \
    *(bf16x8*)(WR) = zown;                                                    \
    asm volatile("s_waitcnt lgkmcnt(0)" ::: "memory");                        \
    __builtin_amdgcn_s_barrier();                                             \
    asm volatile("" ::: "memory");                                            \
  }

#pragma unroll 1
  for (int t = 0; t < Ln; t += 4) {
    PHASE(0, rA1, rA2, rA3, wB)   // t even: read buf0, write buf1
    PHASE(1, rB1, rB2, rB3, wA)
    PHASE(2, rA1, rA2, rA3, wB)
    PHASE(3, rB1, rB2, rB3, wA)
  }
#undef PHASE
#undef SEQ_PF

  // epilogue: h(1024): own tile in zown, foreign tiles in buf0 (t=1023 wrote buf0).
  // Wave w -> vocab tile w (out cols 16w..16w+15).
  {
    const bf16x8 zf1 = *(const bf16x8*)(rA1);
    const bf16x8 zf2 = *(const bf16x8*)(rA2);
    const bf16x8 zf3 = *(const bf16x8*)(rA3);
    const unsigned short* wrow = woutp + (size_t)(16 * w + l15) * En + lg * 8;
    f32x4 o = *(const f32x4*)(b_out + 16 * w + 4 * lg);
    o = MFMA(*(const bf16x8*)(wrow + 32 * w), zown, o, 0, 0, 0);
    o = MFMA(*(const bf16x8*)(wrow + 32 * ((w + 1) & 3)), zf1, o, 0, 0, 0);
    o = MFMA(*(const bf16x8*)(wrow + 32 * ((w + 2) & 3)), zf2, o, 0, 0, 0);
    o = MFMA(*(const bf16x8*)(wrow + 32 * ((w + 3) & 3)), zf3, o, 0, 0, 0);
    *(f32x4*)&out[(size_t)(r0 + l15) * Vn + 16 * w + 4 * lg] = o;
  }
}

// ---------------- round-6 LDS fast path (fallback #1) ----------------

__global__ void rnn_setup_bf(const float* __restrict__ W_in, const float* __restrict__ b_in,
                             const float* __restrict__ W_h, const float* __restrict__ b_h,
                             unsigned short* __restrict__ wallb, float* __restrict__ bc) {
  const int j = blockIdx.x;
  const int k = threadIdx.x;
  const float* whr = W_h + j * (2 * En);
  float s;
  if (k < Vn) {
    s = 0.f;
#pragma unroll 8
    for (int e = 0; e < En; ++e) s = fmaf(W_in[e * Vn + k], whr[e], s);
  } else {
    s = whr[Vn + k];
  }
  wallb[j * Kc + k] = (unsigned short)f2b(s);
  if (k == 0) {
    float b = b_h[j];
    for (int e = 0; e < En; ++e) b = fmaf(b_in[e], whr[e], b);
    bc[j] = b;
  }
}

__global__ __launch_bounds__(128, 1) void rnn_fast2(
    const unsigned short* __restrict__ seqb, const unsigned short* __restrict__ wallb,
    const float* __restrict__ bc, const float* __restrict__ W_out,
    const float* __restrict__ b_out, float* __restrict__ out) {
  __shared__ __align__(16) unsigned char hbB[2][4096];

  const int tid = threadIdx.x;
  const int w   = tid >> 6;
  const int l   = tid & 63;
  const int l15 = l & 15;
  const int lg  = l >> 4;
  const int r0  = blockIdx.x * 16;
  const int swz = (l15 & 7) << 4;

  bf16x8 Aw[4][6];
  f32x4 bcv[4];
#pragma unroll
  for (int nn = 0; nn < 4; ++nn) {
    const int n = 4 * w + nn;
    const unsigned short* p = wallb + (size_t)(16 * n + l15) * Kc + lg * 8;
#pragma unroll
    for (int kt = 0; kt < 6; ++kt) Aw[nn][kt] = *(const bf16x8*)(p + kt * 32);
    bcv[nn] = *(const f32x4*)(bc + 16 * n + 4 * lg);
  }

  for (int i = tid; i < 2048; i += 128) ((unsigned int*)hbB)[i] = 0u;

  const unsigned short* sqb = seqb + ((size_t)(r0 + l15) * Ln) * Vn + lg * 8;
  bf16x8 sreg[4][2];

#define SEQ_PF(BI, T)                                                \
  { const int tp = ((T) < Ln) ? (T) : (Ln - 1);                      \
    const bf16x8* sp = (const bf16x8*)(sqb + (size_t)tp * Vn);       \
    sreg[BI][0] = sp[0];                                             \
    sreg[BI][1] = sp[4]; }

  SEQ_PF(0, 0)
  SEQ_PF(1, 1)
  SEQ_PF(2, 2)
  __syncthreads();

#define PHASE(P)                                                               \
  {                                                                            \
    const int cb = (P) & 1;                                                    \
    const unsigned char* zb = hbB[cb] + l15 * 256;                             \
    const bf16x8 z0 = *(const bf16x8*)(zb + ((16 * lg) ^ swz));                \
    const bf16x8 z1 = *(const bf16x8*)(zb + ((64 + 16 * lg) ^ swz));           \
    const bf16x8 z2 = *(const bf16x8*)(zb + ((128 + 16 * lg) ^ swz));          \
    const bf16x8 z3 = *(const bf16x8*)(zb + ((192 + 16 * lg) ^ swz));          \
    SEQ_PF(((P) + 3) & 3, t + (P) + 3);                                        \
    const bf16x8 s0 = sreg[(P)][0], s1 = sreg[(P)][1];                         \
    f32x4 p0 = bcv[0], p1 = bcv[1], p2 = bcv[2], p3 = bcv[3];                  \
    f32x4 q0 = {0.f, 0.f, 0.f, 0.f}, q1 = {0.f, 0.f, 0.f, 0.f};                \
    f32x4 q2 = {0.f, 0.f, 0.f, 0.f}, q3 = {0.f, 0.f, 0.f, 0.f};                \
    p0 = MFMA(Aw[0][0], s0, p0, 0, 0, 0);                                      \
    p1 = MFMA(Aw[1][0], s0, p1, 0, 0, 0);                                      \
    p2 = MFMA(Aw[2][0], s0, p2, 0, 0, 0);                                      \
    p3 = MFMA(Aw[3][0], s0, p3, 0, 0, 0);                                      \
    q0 = MFMA(Aw[0][1], s1, q0, 0, 0, 0);                                      \
    q1 = MFMA(Aw[1][1], s1, q1, 0, 0, 0);                                      \
    q2 = MFMA(Aw[2][1], s1, q2, 0, 0, 0);                                      \
    q3 = MFMA(Aw[3][1], s1, q3, 0, 0, 0);                                      \
    p0 = MFMA(Aw[0][2], z0, p0, 0, 0, 0);                                      \
    p1 = MFMA(Aw[1][2], z0, p1, 0, 0, 0);                                      \
    p2 = MFMA(Aw[2][2], z0, p2, 0, 0, 0);                                      \
    p3 = MFMA(Aw[3][2], z0, p3, 0, 0, 0);                                      \
    q0 = MFMA(Aw[0][3], z1, q0, 0, 0, 0);                                      \
    q1 = MFMA(Aw[1][3], z1, q1, 0, 0, 0);                                      \
    q2 = MFMA(Aw[2][3], z1, q2, 0, 0, 0);                                      \
    q3 = MFMA(Aw[3][3], z1, q3, 0, 0, 0);                                      \
    p0 = MFMA(Aw[0][4], z2, p0, 0, 0, 0);                                      \
    p1 = MFMA(Aw[1][4], z2, p1, 0, 0, 0);                                      \
    p2 = MFMA(Aw[2][4], z2, p2, 0, 0, 0);                                      \
    p3 = MFMA(Aw[3][4], z2, p3, 0, 0, 0);                                      \
    q0 = MFMA(Aw[0][5], z3, q0, 0, 0, 0);                                      \
    q1 = MFMA(Aw[1][5], z3, q1, 0, 0, 0);                                      \
    q2 = MFMA(Aw[2][5], z3, q2, 0, 0, 0);                                      \
    q3 = MFMA(Aw[3][5], z3, q3, 0, 0, 0);                                      \
    unsigned char* wbB = hbB[cb ^ 1] + l15 * 256;                              \
    _Pragma("unroll") for (int nn = 0; nn < 4; ++nn) {                         \
      const f32x4 pp = (nn == 0) ? p0 : (nn == 1) ? p1 : (nn == 2) ? p2 : p3;  \
      const f32x4 qq = (nn == 0) ? q0 : (nn == 1) ? q1 : (nn == 2) ? q2 : q3;  \
      const float r0v = fmaxf(pp[0] + qq[0], 0.f);                             \
      const float r1v = fmaxf(pp[1] + qq[1], 0.f);                             \
      const float r2v = fmaxf(pp[2] + qq[2], 0.f);                             \
      const float r3v = fmaxf(pp[3] + qq[3], 0.f);                             \
      unsigned d0, d1;                                                         \
      asm("v_cvt_pk_bf16_f32 %0, %1, %2" : "=v"(d0) : "v"(r0v), "v"(r1v));     \
      asm("v_cvt_pk_bf16_f32 %0, %1, %2" : "=v"(d1) : "v"(r2v), "v"(r3v));     \
      uint2 dd; dd.x = d0; dd.y = d1;                                          \
      *(uint2*)(wbB + ((128 * w + 32 * nn + 8 * lg) ^ swz)) = dd;              \
    }                                                                          \
    asm volatile("s_waitcnt lgkmcnt(0)" ::: "memory");                         \
    __builtin_amdgcn_s_barrier();                                              \
    asm volatile("" ::: "memory");                                             \
  }

#pragma unroll 1
  for (int t = 0; t < Ln; t += 4) {
    PHASE(0)
    PHASE(1)
    PHASE(2)
    PHASE(3)
  }
#undef PHASE
#undef SEQ_PF

  bf16x8 hz[4];
  const unsigned char* zb0 = hbB[0] + l15 * 256;
#pragma unroll
  for (int kt = 0; kt < 4; ++kt)
    hz[kt] = *(const bf16x8*)(zb0 + ((64 * kt + 16 * lg) ^ swz));
#pragma unroll
  for (int m = 0; m < 2; ++m) {
    const int v = 16 * (2 * w + m) + l15;
    const float* wor = W_out + (size_t)v * En + lg * 8;
    const float bo = b_out[v];
    f32x4 oa = {bo, bo, bo, bo};
#pragma unroll
    for (int kt = 0; kt < 4; ++kt) {
      float tmp[8];
      const float* p = wor + kt * 32;
#pragma unroll
      for (int i = 0; i < 8; ++i) tmp[i] = p[i];
      oa = MFMA(hz[kt], pack8(tmp), oa, 0, 0, 0);
    }
#pragma unroll
    for (int i = 0; i < 4; ++i)
      out[(size_t)(r0 + 4 * lg + i) * Vn + v] = oa[i];
  }
}

// ---------------- fp32 fallback (no workspace needed) ----------------

__global__ __launch_bounds__(256, 1) void rnn_mfma(
    const float* __restrict__ seq, const float* __restrict__ W_in,
    const float* __restrict__ b_in, const float* __restrict__ W_h,
    const float* __restrict__ b_h, const float* __restrict__ W_out,
    const float* __restrict__ b_out, float* __restrict__ out) {
  __shared__ __align__(16) unsigned short hb[2][16][136];

  const int tid = threadIdx.x;
  const int w   = tid >> 6;
  const int l   = tid & 63;
  const int l15 = l & 15;
  const int lg  = l >> 4;
  const int r0  = blockIdx.x * 16;

  bf16x8 Bw[2][6];
  float bc[2];
#pragma unroll
  for (int n = 0; n < 2; ++n) {
    const int j = 32 * w + 16 * n + l15;
    const float* whr = W_h + j * (2 * En);
    float b = b_h[j];
    for (int e = 0; e < En; ++e) b = fmaf(b_in[e], whr[e], b);
    bc[n] = b;
#pragma unroll
    for (int kt = 0; kt < 6; ++kt) {
      float v[8];
#pragma unroll
      for (int i = 0; i < 8; ++i) {
        const int k = kt * 32 + lg * 8 + i;
        if (k < Vn) {
          float s = 0.f;
          for (int e = 0; e < En; ++e) s = fmaf(W_in[e * Vn + k], whr[e], s);
          v[i] = s;
        } else {
          v[i] = whr[Vn + k];
        }
      }
      Bw[n][kt] = pack8(v);
    }
  }

  for (int i = tid; i < 2 * 16 * 136; i += 256) ((unsigned short*)hb)[i] = 0;

  const float* sq = seq + ((size_t)(r0 + l15) * Ln) * Vn + lg * 8;
  f32x4 sbuf[4][4];

#define SEQ_PF(BI, T)                                                 \
  { const int tp = ((T) < Ln) ? (T) : (Ln - 1);                       \
    const f32x4* p0 = (const f32x4*)(sq + (size_t)tp * Vn);           \
    const f32x4* p1 = (const f32x4*)(sq + (size_t)tp * Vn + 32);      \
    sbuf[BI][0] = p0[0]; sbuf[BI][1] = p0[1];                         \
    sbuf[BI][2] = p1[0]; sbuf[BI][3] = p1[1]; }

  SEQ_PF(0, 0)
  SEQ_PF(1, 1)
  SEQ_PF(2, 2)
  __syncthreads();

#define PHASE(P)                                                              \
  {                                                                           \
    const int cb = (P) & 1, nb = cb ^ 1;                                      \
    const bf16x8 h0 = *(const bf16x8*)&hb[cb][l15][lg * 8];                   \
    const bf16x8 h1 = *(const bf16x8*)&hb[cb][l15][32 + lg * 8];              \
    const bf16x8 h2 = *(const bf16x8*)&hb[cb][l15][64 + lg * 8];              \
    const bf16x8 h3 = *(const bf16x8*)&hb[cb][l15][96 + lg * 8];              \
    SEQ_PF(((P) + 3) & 3, t + (P) + 3);                                       \
    float v0[8], v1[8];                                                       \
    _Pragma("unroll") for (int i = 0; i < 4; ++i) {                           \
      v0[i] = sbuf[(P)][0][i]; v0[4 + i] = sbuf[(P)][1][i];                   \
      v1[i] = sbuf[(P)][2][i]; v1[4 + i] = sbuf[(P)][3][i];                   \
    }                                                                         \
    const bf16x8 a0 = pack8(v0), a1 = pack8(v1);                              \
    f32x4 p0a = {bc[0], bc[0], bc[0], bc[0]};                                 \
    f32x4 p1a = {bc[1], bc[1], bc[1], bc[1]};                                 \
    f32x4 q0a = {0.f, 0.f, 0.f, 0.f}, q1a = {0.f, 0.f, 0.f, 0.f};             \
    p0a = MFMA(a0, Bw[0][0], p0a, 0, 0, 0);                                   \
    p1a = MFMA(a0, Bw[1][0], p1a, 0, 0, 0);                                   \
    p0a = MFMA(a1, Bw[0][1], p0a, 0, 0, 0);                                   \
    p1a = MFMA(a1, Bw[1][1], p1a, 0, 0, 0);                                   \
    p0a = MFMA(h0, Bw[0][2], p0a, 0, 0, 0);                                   \
    p1a = MFMA(h0, Bw[1][2], p1a, 0, 0, 0);                                   \
    q0a = MFMA(h2, Bw[0][4], q0a, 0, 0, 0);                                   \
    q1a = MFMA(h2, Bw[1][4], q1a, 0, 0, 0);                                   \
    p0a = MFMA(h1, Bw[0][3], p0a, 0, 0, 0);                                   \
    p1a = MFMA(h1, Bw[1][3], p1a, 0, 0, 0);                                   \
    q0a = MFMA(h3, Bw[0][5], q0a, 0, 0, 0);                                   \
    q1a = MFMA(h3, Bw[1][5], q1a, 0, 0, 0);                                   \
    const int j0 = 32 * w + l15, j1 = j0 + 16, rr = 4 * lg;                   \
    _Pragma("unroll") for (int i = 0; i < 4; ++i) {                           \
      hb[nb][rr + i][j0] = (unsigned short)f2b(fmaxf(p0a[i] + q0a[i], 0.f));  \
      hb[nb][rr + i][j1] = (unsigned short)f2b(fmaxf(p1a[i] + q1a[i], 0.f));  \
    }                                                                         \
    asm volatile("s_waitcnt lgkmcnt(0)" ::: "memory");                        \
    __builtin_amdgcn_s_barrier();                                             \
    asm volatile("" ::: "memory");                                            \
  }

#pragma unroll 1
  for (int t = 0; t < Ln; t += 4) {
    PHASE(0)
    PHASE(1)
    PHASE(2)
    PHASE(3)
  }
#undef PHASE
#undef SEQ_PF

  const int orow = tid >> 4;
  const int oc   = (tid & 15) * 4;
  float o0 = b_out[oc], o1 = b_out[oc + 1], o2 = b_out[oc + 2], o3 = b_out[oc + 3];
  const float* w0 = W_out + (size_t)(oc + 0) * En;
  const float* w1 = W_out + (size_t)(oc + 1) * En;
  const float* w2 = W_out + (size_t)(oc + 2) * En;
  const float* w3 = W_out + (size_t)(oc + 3) * En;
#pragma unroll 8
  for (int k = 0; k < En; ++k) {
    const float hv = b2f(hb[0][orow][k]);
    o0 = fmaf(hv, w0[k], o0);
    o1 = fmaf(hv, w1[k], o1);
    o2 = fmaf(hv, w2[k], o2);
    o3 = fmaf(hv, w3[k], o3);
  }
  *(float4*)&out[(size_t)(r0 + orow) * Vn + oc] = make_float4(o0, o1, o2, o3);
}

extern "C" void kernel_launch(void* const* d_in, const int* in_sizes, int n_in,
                              void* d_out, int out_size, void* d_ws, size_t ws_size,
                              hipStream_t stream) {
  const float* seq   = (const float*)d_in[0];
  const float* W_in  = (const float*)d_in[1];
  const float* b_in  = (const float*)d_in[2];
  const float* W_h   = (const float*)d_in[3];
  const float* b_h   = (const float*)d_in[4];
  const float* W_out = (const float*)d_in[5];
  const float* b_out = (const float*)d_in[6];
  float* out = (float*)d_out;

  if (ws_size >= FAST_WS2) {
    unsigned short* seqb  = (unsigned short*)d_ws;
    unsigned short* wall2 = (unsigned short*)((char*)d_ws + SEQB_BYTES);
    float* bc             = (float*)((char*)d_ws + SEQB_BYTES + WALLB_BYTES);
    unsigned short* woutp = (unsigned short*)((char*)d_ws + SEQB_BYTES + WALLB_BYTES + BC_BYTES);
    seq_cvt<<<2048, 256, 0, stream>>>(seq, seqb);
    rnn_setup2<<<En, Kc, 0, stream>>>(W_in, b_in, W_h, b_h, wall2, bc);
    wout_setup<<<Vn, En, 0, stream>>>(W_out, woutp);
    rnn_quad<<<Bn / 16, 256, 0, stream>>>(seqb, wall2, bc, woutp, b_out, out);
  } else if (ws_size >= FAST_WS) {
    unsigned short* seqb  = (unsigned short*)d_ws;
    unsigned short* wallb = (unsigned short*)((char*)d_ws + SEQB_BYTES);
    float* bc = (float*)((char*)d_ws + SEQB_BYTES + WALLB_BYTES);
    seq_cvt<<<2048, 256, 0, stream>>>(seq, seqb);
    rnn_setup_bf<<<En, Kc, 0, stream>>>(W_in, b_in, W_h, b_h, wallb, bc);
    rnn_fast2<<<Bn / 16, 128, 0, stream>>>(seqb, wallb, bc, W_out, b_out, out);
  } else {
    rnn_mfma<<<Bn / 16, 256, 0, stream>>>(seq, W_in, b_in, W_h, b_h, W_out, b_out, out);
  }
}